// Round 14
// baseline (6619.852 us; speedup 1.0000x reference)
//
#include <hip/hip_runtime.h>

// Problem dims (fixed)
#define Bn 64
#define Tn 512
#define En 1024
#define Hn 1024
#define Vn 50257
#define CHUNK 64
#define NCHUNK (Tn / CHUNK)
#define AGENT __HIP_MEMORY_SCOPE_AGENT

typedef __attribute__((ext_vector_type(8))) short short8;
typedef __attribute__((ext_vector_type(4))) float f32x4;
typedef __attribute__((ext_vector_type(4))) unsigned int u32x4;

__device__ __forceinline__ unsigned short f2bf(float f) {
    union { float f; unsigned u; } x; x.f = f;
    unsigned r = x.u + 0x7FFFu + ((x.u >> 16) & 1u);   // RNE; values are tame
    return (unsigned short)(r >> 16);
}
__device__ __forceinline__ float bf2f(unsigned short u) {
    union { unsigned u; float f; } x; x.u = ((unsigned)u) << 16; return x.f;
}
__device__ __forceinline__ float sigm(float x) { return 1.0f / (1.0f + __expf(-x)); }
__device__ __forceinline__ float tanh_fast(float x) {
    float e = __expf(2.0f * x);
    return (e - 1.0f) / (e + 1.0f);
}

// 16B IC-coherent load (bypasses L1/L2 -> coherent at Infinity Cache)
#define LDH(dst, base, IMM)                                                  \
    asm volatile("global_load_dwordx4 %0, %1, off offset:" #IMM " sc0 sc1"   \
                 : "=v"(dst) : "v"(base) : "memory")
// counted wait + scheduler fence (rule #18)
#define VMW(N) do { asm volatile("s_waitcnt vmcnt(" #N ")" ::: "memory");    \
                    __builtin_amdgcn_sched_barrier(0); } while (0)
// issue one group of 8 16B h-loads (2 row-tiles x 4 consecutive j)
#define ISSUE_GRP(buf, O0, O1, O2, O3)                                       \
    do {                                                                     \
        LDH((buf)[0], ap0, O0); LDH((buf)[1], ap0, O1);                      \
        LDH((buf)[2], ap0, O2); LDH((buf)[3], ap0, O3);                      \
        LDH((buf)[4], ap1, O0); LDH((buf)[5], ap1, O1);                      \
        LDH((buf)[6], ap1, O2); LDH((buf)[7], ap1, O3);                      \
    } while (0)
// consume 8 fragments against breg[ct][jb..jb+3]
#define MFMA_GRP(buf, jb)                                                    \
    do {                                                                     \
        _Pragma("unroll")                                                    \
        for (int jj = 0; jj < 4; ++jj) {                                     \
            union { u32x4 u; short8 s; } f0, f1;                             \
            f0.u = (buf)[jj]; f1.u = (buf)[4 + jj];                          \
            acc[0][0] = __builtin_amdgcn_mfma_f32_16x16x32_bf16(f0.s, breg[0][(jb) + jj], acc[0][0], 0, 0, 0); \
            acc[0][1] = __builtin_amdgcn_mfma_f32_16x16x32_bf16(f0.s, breg[1][(jb) + jj], acc[0][1], 0, 0, 0); \
            acc[1][0] = __builtin_amdgcn_mfma_f32_16x16x32_bf16(f1.s, breg[0][(jb) + jj], acc[1][0], 0, 0, 0); \
            acc[1][1] = __builtin_amdgcn_mfma_f32_16x16x32_bf16(f1.s, breg[1][(jb) + jj], acc[1][1], 0, 0, 0); \
        }                                                                    \
    } while (0)

// OR of tag-bit mismatches across a group's 32 words (bits 0/16 carry bf16 LSBs)
__device__ __forceinline__ unsigned tagmask8(const u32x4* buf, unsigned expw) {
    unsigned m = 0;
#pragma unroll
    for (int i = 0; i < 8; ++i) {
        u32x4 v = buf[i];
        m |= (v[0] ^ expw) | (v[1] ^ expw) | (v[2] ^ expw) | (v[3] ^ expw);
    }
    return m & 0x00010001u;
}
// freshness retry: if any lane sees a stale tag, re-issue the group and drain
#define RETRY_GRP(buf, O0, O1, O2, O3)                                       \
    do {                                                                     \
        unsigned m_ = tagmask8(buf, expw);                                   \
        int g_ = 0;                                                          \
        while (__any(m_ != 0) && g_ < (1 << 14)) {                           \
            ISSUE_GRP(buf, O0, O1, O2, O3);                                  \
            VMW(0);                                                          \
            m_ = tagmask8(buf, expw);                                        \
            ++g_;                                                            \
        }                                                                    \
    } while (0)

// ---------------- fp32 -> bf16 weight convert ----------------
__global__ __launch_bounds__(256)
void cvt_f32_bf16(const float* __restrict__ src, unsigned short* __restrict__ dst, int n4) {
    int i = blockIdx.x * 256 + threadIdx.x;
    if (i < n4) {
        float4 v = reinterpret_cast<const float4*>(src)[i];
        ushort4 o;
        o.x = f2bf(v.x); o.y = f2bf(v.y); o.z = f2bf(v.z); o.w = f2bf(v.w);
        reinterpret_cast<ushort4*>(dst)[i] = o;
    }
}

// ---------------- embedding gather for one 64-step chunk ----------------
__global__ __launch_bounds__(256)
void gather_x(const int* __restrict__ tokens, const float* __restrict__ emb,
              unsigned short* __restrict__ X, int t0) {
    const int r = blockIdx.x;
    const int trel = r >> 6, b = r & 63;
    const int tok = tokens[b * Tn + t0 + trel];
    const float* src = emb + (size_t)tok * En;
    const int k = threadIdx.x * 4;
    float4 v = *reinterpret_cast<const float4*>(src + k);
    ushort4 o;
    o.x = f2bf(v.x); o.y = f2bf(v.y); o.z = f2bf(v.z); o.w = f2bf(v.w);
    *reinterpret_cast<ushort4*>(X + (size_t)r * En + k) = o;
}

// ---- shared gemm tile body: one 128x128 tile of X @ Wih^T (bf16 out) ----
__device__ __forceinline__ void gemm_tile(
    const unsigned short* __restrict__ X, const unsigned short* __restrict__ Wih,
    unsigned short* __restrict__ G, int bx, int by,
    unsigned short (*As)[72], unsigned short (*Bs)[72], int tid)
{
    const int w = tid >> 6, l = tid & 63;
    const int wr = w >> 1, wc = w & 1;
    const int koff = (l >> 4) * 8;

    f32x4 acc[4][4];
#pragma unroll
    for (int i = 0; i < 4; ++i)
#pragma unroll
        for (int j = 0; j < 4; ++j) acc[i][j] = (f32x4){0.f, 0.f, 0.f, 0.f};

    for (int kk = 0; kk < En / 64; ++kk) {
        __syncthreads();
#pragma unroll
        for (int j = 0; j < 4; ++j) {
            const int u = tid * 4 + j;
            const int row = u >> 3, ku = (u & 7) * 8;
            *reinterpret_cast<short8*>(&As[row][ku]) =
                *reinterpret_cast<const short8*>(X + (size_t)(by * 128 + row) * En + kk * 64 + ku);
            *reinterpret_cast<short8*>(&Bs[row][ku]) =
                *reinterpret_cast<const short8*>(Wih + (size_t)(bx * 128 + row) * En + kk * 64 + ku);
        }
        __syncthreads();

#pragma unroll
        for (int kc = 0; kc < 2; ++kc) {
            const int k0 = kc * 32 + koff;
            short8 af[4], bf[4];
#pragma unroll
            for (int i = 0; i < 4; ++i)
                af[i] = *reinterpret_cast<const short8*>(&As[wr * 64 + i * 16 + (l & 15)][k0]);
#pragma unroll
            for (int j = 0; j < 4; ++j)
                bf[j] = *reinterpret_cast<const short8*>(&Bs[wc * 64 + j * 16 + (l & 15)][k0]);
#pragma unroll
            for (int i = 0; i < 4; ++i)
#pragma unroll
                for (int j = 0; j < 4; ++j)
                    acc[i][j] = __builtin_amdgcn_mfma_f32_16x16x32_bf16(af[i], bf[j], acc[i][j], 0, 0, 0);
        }
    }

    const int rr = 4 * (l >> 4);
#pragma unroll
    for (int i = 0; i < 4; ++i) {
        const int row = by * 128 + wr * 64 + i * 16 + rr;
#pragma unroll
        for (int j = 0; j < 4; ++j) {
            const int col = bx * 128 + wc * 64 + j * 16 + (l & 15);
#pragma unroll
            for (int r = 0; r < 4; ++r)
                G[(size_t)(row + r) * 4096 + col] = f2bf(acc[i][j][r]);
        }
    }
}

// ---------------- standalone G = X @ W_ih^T (chunk 0 only), bf16 out ----------------
__global__ __launch_bounds__(256)
void gemm_gin(const unsigned short* __restrict__ X, const unsigned short* __restrict__ Wih,
              unsigned short* __restrict__ G) {
    __shared__ __align__(16) unsigned short As[128][72];
    __shared__ __align__(16) unsigned short Bs[128][72];
    gemm_tile(X, Wih, G, blockIdx.x & 31, blockIdx.x >> 5, As, Bs, threadIdx.x);
}

// ---------------- fused: recurrence (blocks 0-127) + next-chunk GEMM (128-255) ----
// TAGGED-DATA SYNC: h exchanged with each bf16's LSB forced to (t+1)&1.
// Consumers load data directly (no flag poll); stale tags -> re-issue group.
// 3 rotating h buffers (odd count -> stale parity always differs). Stores are
// fire-and-forget (no drain). Flags only back the LAGGED write-guard (all
// flags >= t-1 before overwriting slot (t+1)%3 = h(t-2)) and are stored EARLY
// (post-MFMA, reads provably done). LDS red double-buffered by step parity.
__global__ __launch_bounds__(256, 1)
void lstm_fused(const unsigned short* __restrict__ Gcur, unsigned short* __restrict__ Gnext,
                const unsigned short* __restrict__ Xnext, const unsigned short* __restrict__ Wih,
                const unsigned short* __restrict__ Whh,
                unsigned short* __restrict__ hb0, unsigned short* __restrict__ hb1,
                unsigned short* __restrict__ hb2, unsigned short* __restrict__ hclean,
                float* __restrict__ c_state, unsigned* __restrict__ flags, int t0, int do_gemm,
                float* __restrict__ out_h, float* __restrict__ out_c)
{
    __shared__ __align__(16) char smem[2 * 128 * 72 * 2];   // 36 KB (gemm As/Bs; recurrence red[2] 32 KB)

    const int tid = threadIdx.x;

    if (blockIdx.x >= 128) {
        // ---- GEMM half: 8 tiles of G(next chunk); no sync participation ----
        if (!do_gemm) return;
        unsigned short (*As)[72] = reinterpret_cast<unsigned short(*)[72]>(smem);
        unsigned short (*Bs)[72] = reinterpret_cast<unsigned short(*)[72]>(smem + 128 * 72 * 2);
        const int base = (blockIdx.x - 128) * 8;
        for (int tt = 0; tt < 8; ++tt) {
            const int tile = base + tt;
            gemm_tile(Xnext, Wih, Gnext, tile & 31, tile >> 5, As, Bs, tid);
        }
        return;
    }

    // ---- recurrence half ----
    typedef float RedT[2][2][64][4];                 // [rt][ct][lane][r]

    const int b = blockIdx.x;
    const int w = tid >> 6, l = tid & 63;
    const int kh = w & 1, rh = w >> 1;
    const int koff = (l >> 4) * 8;
    const int lc = l & 15;
    const int hcol = b * 8 + (l & 7);

    // W_hh fragments -> registers (once per launch)
    short8 breg[2][16];
#pragma unroll
    for (int ct = 0; ct < 2; ++ct) {
        const int gate = ct * 2 + (lc >> 3);
        const unsigned short* wrow = Whh + ((size_t)gate * Hn + (b * 8 + (lc & 7))) * Hn;
#pragma unroll
        for (int j = 0; j < 16; ++j)
            breg[ct][j] = *reinterpret_cast<const short8*>(wrow + (kh * 16 + j) * 32 + koff);
    }

    // c-state in registers (kh==0 waves own the cell update)
    float c_reg[2][4];
    if (kh == 0) {
#pragma unroll
        for (int rt = 0; rt < 2; ++rt)
#pragma unroll
            for (int r = 0; r < 4; ++r)
                c_reg[rt][r] = c_state[(rh * 32 + rt * 16 + ((l >> 4) << 2) + r) * Hn + hcol];
    }

    const int sg = lc >> 3;
    const int gc0 = sg * Hn + hcol;          // i (sg=0) / f (sg=1)
    const int gc1 = (2 + sg) * Hn + hcol;    // g / o

    // prologue: prefetch G(s=0), bf16
    unsigned short gp0[2][4], gp1[2][4];
    if (kh == 0) {
#pragma unroll
        for (int rt = 0; rt < 2; ++rt) {
            const int rowbase = rh * 32 + rt * 16 + ((l >> 4) << 2);
#pragma unroll
            for (int r = 0; r < 4; ++r) {
                gp0[rt][r] = Gcur[(size_t)(rowbase + r) * 4096 + gc0];
                gp1[rt][r] = Gcur[(size_t)(rowbase + r) * 4096 + gc1];
            }
        }
    }

    for (int s = 0; s < CHUNK; ++s) {
        const int t = t0 + s;
        const unsigned short* hin  = (t % 3 == 0) ? hb0 : ((t % 3 == 1) ? hb1 : hb2);
        unsigned short*       hout = ((t + 1) % 3 == 0) ? hb0 : (((t + 1) % 3 == 1) ? hb1 : hb2);
        const unsigned expw = (t & 1) ? 0x00010001u : 0u;        // S_t tag parity
        const unsigned tb   = (unsigned)((t + 1) & 1);           // tag for S_{t+1}

        const unsigned short* ap0 =
            hin + (size_t)(rh * 32 + (l & 15)) * Hn + kh * 512 + koff;
        const unsigned short* ap1 =
            hin + (size_t)(rh * 32 + 16 + (l & 15)) * Hn + kh * 512 + koff;

        f32x4 acc[2][2];
        acc[0][0] = acc[0][1] = acc[1][0] = acc[1][1] = (f32x4){0.f, 0.f, 0.f, 0.f};

        u32x4 bufA[8], bufB[8], bufC[8], bufD[8];
        ISSUE_GRP(bufA, 0,   64,  128, 192);   // j = 0..3
        ISSUE_GRP(bufB, 256, 320, 384, 448);   // j = 4..7
        ISSUE_GRP(bufC, 512, 576, 640, 704);   // j = 8..11
        ISSUE_GRP(bufD, 768, 832, 896, 960);   // j = 12..15

        VMW(24); RETRY_GRP(bufA, 0,   64,  128, 192); MFMA_GRP(bufA, 0);
        VMW(16); RETRY_GRP(bufB, 256, 320, 384, 448); MFMA_GRP(bufB, 4);
        VMW(8);  RETRY_GRP(bufC, 512, 576, 640, 704); MFMA_GRP(bufC, 8);
        VMW(0);  RETRY_GRP(bufD, 768, 832, 896, 960); MFMA_GRP(bufD, 12);

        // K-split reduction via LDS (double-buffered by step parity)
        RedT* red = reinterpret_cast<RedT*>(smem + (t & 1) * 16384);
        if (kh == 1) {
#pragma unroll
            for (int rt = 0; rt < 2; ++rt)
#pragma unroll
                for (int ct = 0; ct < 2; ++ct)
                    *reinterpret_cast<f32x4*>(&red[rh][rt][ct][l][0]) = acc[rt][ct];
        }
        __syncthreads();   // all waves past MFMA -> all reads of S_t done

        // early arrive: "block completed step t" (read-completion semantics)
        if (tid == 0)
            __hip_atomic_store(&flags[b * 32], (unsigned)(t + 1), __ATOMIC_RELAXED, AGENT);

        if (kh == 0) {
            // lagged write-guard: writing S_{t+1} into slot (t+1)%3 clobbers
            // S_{t-2}; require all blocks completed step t-2 (flags >= t-1).
            if (t >= 2) {
                const unsigned tgt2 = (unsigned)(t - 1);
                unsigned fa = __hip_atomic_load(&flags[l * 32], __ATOMIC_RELAXED, AGENT);
                unsigned fbv = __hip_atomic_load(&flags[(64 + l) * 32], __ATOMIC_RELAXED, AGENT);
                int guard = 0;
                while (__any((fa < tgt2) || (fbv < tgt2)) && guard < (1 << 16)) {
                    __builtin_amdgcn_s_sleep(1);
                    fa = __hip_atomic_load(&flags[l * 32], __ATOMIC_RELAXED, AGENT);
                    fbv = __hip_atomic_load(&flags[(64 + l) * 32], __ATOMIC_RELAXED, AGENT);
                    ++guard;
                }
            }

#pragma unroll
            for (int rt = 0; rt < 2; ++rt) {
                const int rowbase = rh * 32 + rt * 16 + ((l >> 4) << 2);
                f32x4 a0 = acc[rt][0] + *reinterpret_cast<f32x4*>(&red[rh][rt][0][l][0]);
                f32x4 a1 = acc[rt][1] + *reinterpret_cast<f32x4*>(&red[rh][rt][1][l][0]);
#pragma unroll
                for (int r = 0; r < 4; ++r) {
                    float v0 = a0[r] + bf2f(gp0[rt][r]);
                    float v1 = a1[r] + bf2f(gp1[rt][r]);
                    float p0 = __shfl_xor(v0, 8);
                    float p1 = __shfl_xor(v1, 8);
                    float iv = (l & 8) ? p0 : v0;
                    float fv = (l & 8) ? v0 : p0;
                    float gv = (l & 8) ? p1 : v1;
                    float ov = (l & 8) ? v1 : p1;
                    float cn = sigm(fv) * c_reg[rt][r] + sigm(iv) * tanh_fast(gv);
                    float hn = sigm(ov) * tanh_fast(cn);
                    c_reg[rt][r] = cn;
                    unsigned hb = ((unsigned)f2bf(hn) & 0xFFFEu) | tb;   // LSB = step tag
                    unsigned partner = (unsigned)__shfl_xor((int)hb, 1);
                    if (!(l & 8) && !(l & 1)) {
                        unsigned val = (hb & 0xFFFFu) | (partner << 16);
                        __hip_atomic_store(
                            (unsigned*)(hout + (size_t)(rowbase + r) * Hn + hcol),
                            val, __ATOMIC_RELAXED, AGENT);     // fire-and-forget
                    }
                    if (t == Tn - 1 && !(l & 8)) {
                        out_h[(rowbase + r) * Hn + hcol] = hn;
                        out_c[(rowbase + r) * Hn + hcol] = cn;
                        hclean[(rowbase + r) * Hn + hcol] = f2bf(hn);   // untagged for classifier
                    }
                }
            }

            // prefetch G(s+1): sits in queue, retired by next step's VMW(24)
            if (s + 1 < CHUNK) {
                const unsigned short* Gt = Gcur + (size_t)(s + 1) * Bn * 4096;
#pragma unroll
                for (int rt = 0; rt < 2; ++rt) {
                    const int rowbase = rh * 32 + rt * 16 + ((l >> 4) << 2);
#pragma unroll
                    for (int r = 0; r < 4; ++r) {
                        gp0[rt][r] = Gt[(size_t)(rowbase + r) * 4096 + gc0];
                        gp1[rt][r] = Gt[(size_t)(rowbase + r) * 4096 + gc1];
                    }
                }
            }
        }
        // no end-of-step barrier: tags gate the next step's data
    }

    if (kh == 0 && !(l & 8)) {
#pragma unroll
        for (int rt = 0; rt < 2; ++rt)
#pragma unroll
            for (int r = 0; r < 4; ++r)
                c_state[(rh * 32 + rt * 16 + ((l >> 4) << 2) + r) * Hn + hcol] = c_reg[rt][r];
    }
}

// ---------------- classifier: logits[64,V] = h @ W_cls^T + b ----------------
__global__ __launch_bounds__(256)
void classifier(const unsigned short* __restrict__ h,
                const float* __restrict__ Wcls, const float* __restrict__ bcls,
                float* __restrict__ logits)
{
    __shared__ __align__(16) unsigned short Al[64][72];
    __shared__ __align__(16) unsigned short Bl[64][72];

    const int tid = threadIdx.x;
    const int v0 = blockIdx.x * 64;
    const int w = tid >> 6, l = tid & 63;
    const int lrow = tid >> 2, q = tid & 3;
    const int v = v0 + lrow;

    const unsigned short* hrow = h + lrow * Hn;
    const float* wrow = Wcls + (size_t)v * Hn;

    f32x4 acc[4];
#pragma unroll
    for (int ct = 0; ct < 4; ++ct) acc[ct] = (f32x4){0.f, 0.f, 0.f, 0.f};

    const int arow = w * 16 + (l & 15);
    const int koff = (l >> 4) * 8;

    for (int ch = 0; ch < 16; ++ch) {
        const int k0 = ch * 64;
        __syncthreads();
#pragma unroll
        for (int i2 = 0; i2 < 4; ++i2) {
            const int k = q * 4 + i2 * 16;
            *reinterpret_cast<ushort4*>(&Al[lrow][k]) =
                *reinterpret_cast<const ushort4*>(hrow + k0 + k);
            if (v < Vn) {
                float4 x = *reinterpret_cast<const float4*>(wrow + k0 + k);
                Bl[lrow][k + 0] = f2bf(x.x); Bl[lrow][k + 1] = f2bf(x.y);
                Bl[lrow][k + 2] = f2bf(x.z); Bl[lrow][k + 3] = f2bf(x.w);
            } else {
                ushort4 z; z.x = z.y = z.z = z.w = 0;
                *reinterpret_cast<ushort4*>(&Bl[lrow][k]) = z;
            }
        }
        __syncthreads();

        short8 a0 = *reinterpret_cast<const short8*>(&Al[arow][koff]);
        short8 a1 = *reinterpret_cast<const short8*>(&Al[arow][32 + koff]);
#pragma unroll
        for (int ct = 0; ct < 4; ++ct) {
            const int bcol = ct * 16 + (l & 15);
            short8 b0 = *reinterpret_cast<const short8*>(&Bl[bcol][koff]);
            short8 b1 = *reinterpret_cast<const short8*>(&Bl[bcol][32 + koff]);
            acc[ct] = __builtin_amdgcn_mfma_f32_16x16x32_bf16(a0, b0, acc[ct], 0, 0, 0);
            acc[ct] = __builtin_amdgcn_mfma_f32_16x16x32_bf16(a1, b1, acc[ct], 0, 0, 0);
        }
    }

    const int rr0 = w * 16 + (l >> 4) * 4;
#pragma unroll
    for (int ct = 0; ct < 4; ++ct) {
        const int vv = v0 + ct * 16 + (l & 15);
        if (vv < Vn) {
            float bb = bcls[vv];
#pragma unroll
            for (int r = 0; r < 4; ++r)
                logits[(size_t)(rr0 + r) * Vn + vv] = acc[ct][r] + bb;
        }
    }
}

extern "C" void kernel_launch(void* const* d_in, const int* in_sizes, int n_in,
                              void* d_out, int out_size, void* d_ws, size_t ws_size,
                              hipStream_t stream)
{
    const int*   tokens = (const int*)d_in[0];
    const float* emb    = (const float*)d_in[1];
    const float* W_ih   = (const float*)d_in[2];
    const float* W_hh   = (const float*)d_in[3];
    const float* W_cls  = (const float*)d_in[4];
    const float* b_cls  = (const float*)d_in[5];
    float* out = (float*)d_out;

    // ws layout (~88.8 MB):
    // [hb0 128K][hb1 128K][hb2 128K][hclean 128K][c 256K][flags 16K][Wih 8M][Whh 8M][X 8M][G0 32M][G1 32M]
    char* ws = (char*)d_ws;
    unsigned short* hbuf0  = (unsigned short*)ws;
    unsigned short* hbuf1  = (unsigned short*)(ws + 131072);
    unsigned short* hbuf2  = (unsigned short*)(ws + 262144);
    unsigned short* hclean = (unsigned short*)(ws + 393216);
    float*          cst    = (float*)(ws + 524288);
    unsigned*       flags  = (unsigned*)(ws + 786432);
    unsigned short* Wih_b  = (unsigned short*)(ws + 802816);
    unsigned short* Whh_b  = (unsigned short*)(ws + 802816 + 8388608);
    unsigned short* Xb     = (unsigned short*)(ws + 802816 + 2 * 8388608);
    unsigned short* Gb0    = (unsigned short*)(ws + 802816 + 3 * 8388608);
    unsigned short* Gb1    = (unsigned short*)(ws + 802816 + 3 * 8388608 + 33554432);

    // init: hb0,hb1 = 0 (parity 0); hb2 = 0x01 bytes (parity 1, can't alias
    // the parity-0 expectation at its first use t=2); hclean/c/flags = 0
    hipMemsetAsync(ws, 0, 262144, stream);
    hipMemsetAsync(ws + 262144, 0x01, 131072, stream);
    hipMemsetAsync(ws + 393216, 0, 409600, stream);

    const int n4 = (4 * Hn * En) / 4;
    cvt_f32_bf16<<<n4 / 256, 256, 0, stream>>>(W_ih, Wih_b, n4);
    cvt_f32_bf16<<<n4 / 256, 256, 0, stream>>>(W_hh, Whh_b, n4);

    float* out_h = out + (size_t)Bn * Vn;
    float* out_c = out_h + Bn * Hn;

    // chunk 0: gather + standalone gemm
    gather_x<<<CHUNK * Bn, 256, 0, stream>>>(tokens, emb, Xb, 0);
    gemm_gin<<<32 * 32, 256, 0, stream>>>(Xb, Wih_b, Gb0);

    unsigned short* Gbuf[2] = {Gb0, Gb1};
    for (int c = 0; c < NCHUNK; ++c) {
        const int do_gemm = (c + 1 < NCHUNK) ? 1 : 0;
        if (do_gemm)
            gather_x<<<CHUNK * Bn, 256, 0, stream>>>(tokens, emb, Xb, (c + 1) * CHUNK);
        lstm_fused<<<256, 256, 0, stream>>>(Gbuf[c & 1], Gbuf[(c + 1) & 1], Xb,
                                            Wih_b, Whh_b, hbuf0, hbuf1, hbuf2, hclean,
                                            cst, flags, c * CHUNK, do_gemm,
                                            out_h, out_c);
    }

    classifier<<<(Vn + 63) / 64, 256, 0, stream>>>(hclean, W_cls, b_cls, out);
}

// Round 15
// 5033.923 us; speedup vs baseline: 1.3150x; 1.3150x over previous
//
#include <hip/hip_runtime.h>

// Problem dims (fixed)
#define Bn 64
#define Tn 512
#define En 1024
#define Hn 1024
#define Vn 50257
#define CHUNK 64
#define NCHUNK (Tn / CHUNK)
#define AGENT __HIP_MEMORY_SCOPE_AGENT

typedef __attribute__((ext_vector_type(8))) short short8;
typedef __attribute__((ext_vector_type(4))) float f32x4;
typedef __attribute__((ext_vector_type(4))) unsigned int u32x4;

__device__ __forceinline__ unsigned short f2bf(float f) {
    union { float f; unsigned u; } x; x.f = f;
    unsigned r = x.u + 0x7FFFu + ((x.u >> 16) & 1u);   // RNE; values are tame
    return (unsigned short)(r >> 16);
}
__device__ __forceinline__ float bf2f(unsigned short u) {
    union { unsigned u; float f; } x; x.u = ((unsigned)u) << 16; return x.f;
}
__device__ __forceinline__ float sigm(float x) { return 1.0f / (1.0f + __expf(-x)); }
__device__ __forceinline__ float tanh_fast(float x) {
    float e = __expf(2.0f * x);
    return (e - 1.0f) / (e + 1.0f);
}

// 16B IC-coherent load (bypasses L1/L2 -> coherent at Infinity Cache)
#define LDH(dst, base, IMM)                                                  \
    asm volatile("global_load_dwordx4 %0, %1, off offset:" #IMM " sc0 sc1"   \
                 : "=v"(dst) : "v"(base) : "memory")
// 16B IC-coherent store with imm offset
#define STHI(addr, data, IMM)                                                \
    asm volatile("global_store_dwordx4 %0, %1, off offset:" #IMM " sc0 sc1"  \
                 :: "v"(addr), "v"(data) : "memory")
// counted wait + scheduler fence (rule #18)
#define VMW(N) do { asm volatile("s_waitcnt vmcnt(" #N ")" ::: "memory");    \
                    __builtin_amdgcn_sched_barrier(0); } while (0)
// issue one group of 8 16B h-loads (2 row-tiles x 4 consecutive j)
#define ISSUE_GRP(buf, O0, O1, O2, O3)                                       \
    do {                                                                     \
        LDH((buf)[0], ap0, O0); LDH((buf)[1], ap0, O1);                      \
        LDH((buf)[2], ap0, O2); LDH((buf)[3], ap0, O3);                      \
        LDH((buf)[4], ap1, O0); LDH((buf)[5], ap1, O1);                      \
        LDH((buf)[6], ap1, O2); LDH((buf)[7], ap1, O3);                      \
    } while (0)
// consume 8 A-fragments (2 rt x 4 j) against breg[ct][jb..jb+3], 4 col-tiles
#define MFMA_G4(buf, jb)                                                     \
    do {                                                                     \
        _Pragma("unroll")                                                    \
        for (int jj = 0; jj < 4; ++jj) {                                     \
            union { u32x4 u; short8 s; } f0, f1;                             \
            f0.u = (buf)[jj]; f1.u = (buf)[4 + jj];                          \
            _Pragma("unroll")                                                \
            for (int ct = 0; ct < 4; ++ct) {                                 \
                acc[0][ct] = __builtin_amdgcn_mfma_f32_16x16x32_bf16(f0.s, breg[ct][(jb) + jj], acc[0][ct], 0, 0, 0); \
                acc[1][ct] = __builtin_amdgcn_mfma_f32_16x16x32_bf16(f1.s, breg[ct][(jb) + jj], acc[1][ct], 0, 0, 0); \
            }                                                                \
        }                                                                    \
    } while (0)

// ---------------- fp32 -> bf16 weight convert ----------------
__global__ __launch_bounds__(256)
void cvt_f32_bf16(const float* __restrict__ src, unsigned short* __restrict__ dst, int n4) {
    int i = blockIdx.x * 256 + threadIdx.x;
    if (i < n4) {
        float4 v = reinterpret_cast<const float4*>(src)[i];
        ushort4 o;
        o.x = f2bf(v.x); o.y = f2bf(v.y); o.z = f2bf(v.z); o.w = f2bf(v.w);
        reinterpret_cast<ushort4*>(dst)[i] = o;
    }
}

// ---------------- embedding gather for one 64-step chunk ----------------
__global__ __launch_bounds__(256)
void gather_x(const int* __restrict__ tokens, const float* __restrict__ emb,
              unsigned short* __restrict__ X, int t0) {
    const int r = blockIdx.x;
    const int trel = r >> 6, b = r & 63;
    const int tok = tokens[b * Tn + t0 + trel];
    const float* src = emb + (size_t)tok * En;
    const int k = threadIdx.x * 4;
    float4 v = *reinterpret_cast<const float4*>(src + k);
    ushort4 o;
    o.x = f2bf(v.x); o.y = f2bf(v.y); o.z = f2bf(v.z); o.w = f2bf(v.w);
    *reinterpret_cast<ushort4*>(X + (size_t)r * En + k) = o;
}

// ---- gemm tile body: one 128x128 tile of X @ Wih^T, output TRANSPOSED bf16:
//      G2[s][col 4096][row 64], elem addr = s*262144 + col*64 + (grow & 63)
__device__ __forceinline__ void gemm_tile(
    const unsigned short* __restrict__ X, const unsigned short* __restrict__ Wih,
    unsigned short* __restrict__ G2, int bx, int by,
    unsigned short (*As)[72], unsigned short (*Bs)[72], int tid)
{
    const int w = tid >> 6, l = tid & 63;
    const int wr = w >> 1, wc = w & 1;
    const int koff = (l >> 4) * 8;

    f32x4 acc[4][4];
#pragma unroll
    for (int i = 0; i < 4; ++i)
#pragma unroll
        for (int j = 0; j < 4; ++j) acc[i][j] = (f32x4){0.f, 0.f, 0.f, 0.f};

    for (int kk = 0; kk < En / 64; ++kk) {
        __syncthreads();
#pragma unroll
        for (int j = 0; j < 4; ++j) {
            const int u = tid * 4 + j;
            const int row = u >> 3, ku = (u & 7) * 8;
            *reinterpret_cast<short8*>(&As[row][ku]) =
                *reinterpret_cast<const short8*>(X + (size_t)(by * 128 + row) * En + kk * 64 + ku);
            *reinterpret_cast<short8*>(&Bs[row][ku]) =
                *reinterpret_cast<const short8*>(Wih + (size_t)(bx * 128 + row) * En + kk * 64 + ku);
        }
        __syncthreads();

#pragma unroll
        for (int kc = 0; kc < 2; ++kc) {
            const int k0 = kc * 32 + koff;
            short8 af[4], bf[4];
#pragma unroll
            for (int i = 0; i < 4; ++i)
                af[i] = *reinterpret_cast<const short8*>(&As[wr * 64 + i * 16 + (l & 15)][k0]);
#pragma unroll
            for (int j = 0; j < 4; ++j)
                bf[j] = *reinterpret_cast<const short8*>(&Bs[wc * 64 + j * 16 + (l & 15)][k0]);
#pragma unroll
            for (int i = 0; i < 4; ++i)
#pragma unroll
                for (int j = 0; j < 4; ++j)
                    acc[i][j] = __builtin_amdgcn_mfma_f32_16x16x32_bf16(af[i], bf[j], acc[i][j], 0, 0, 0);
        }
    }

    const int rr = 4 * (l >> 4);
#pragma unroll
    for (int i = 0; i < 4; ++i) {
        const int grow = by * 128 + wr * 64 + i * 16 + rr;   // grow..grow+3 same s
        const int sI = grow >> 6, br = grow & 63;
#pragma unroll
        for (int j = 0; j < 4; ++j) {
            const int col = bx * 128 + wc * 64 + j * 16 + (l & 15);
            ushort4 o;
            o.x = f2bf(acc[i][j][0]); o.y = f2bf(acc[i][j][1]);
            o.z = f2bf(acc[i][j][2]); o.w = f2bf(acc[i][j][3]);
            *reinterpret_cast<ushort4*>(G2 + (size_t)sI * 262144 + (size_t)col * 64 + br) = o;
        }
    }
}

// ---------------- standalone G2 = X @ W_ih^T (chunk 0 only) ----------------
__global__ __launch_bounds__(256)
void gemm_gin(const unsigned short* __restrict__ X, const unsigned short* __restrict__ Wih,
              unsigned short* __restrict__ G2) {
    __shared__ __align__(16) unsigned short As[128][72];
    __shared__ __align__(16) unsigned short Bs[128][72];
    gemm_tile(X, Wih, G2, blockIdx.x & 31, blockIdx.x >> 5, As, Bs, threadIdx.x);
}

// ---------------- fused: K-split recurrence (0-127) + next-chunk GEMM (128-255) ----
// 64 PAIRS: front block b (<64) owns cols {gate ct, hcol b*16+lc} with K in
// [0,512); back block b+64 same cols, K in [512,1024). Per-CU h ingest = 64KB
// (halved). Waves (rh=w>>1, kh2=w&1): rows rh*32..+32, K-quarter kh2 -- h read
// exactly once per block. Back writes 16KB fp32 partial (front's acc layout)
// + pflag; front adds partial post-MFMA, cell has all 4 gates lane-local.
// Sync: fronts-only rigid flag barrier (64 flags); back-read completion is
// certified transitively (front flag(t) => consumed partial(t) => back read
// h(t)). Dep graph fronts(t-1)->backs(t)->fronts(t): acyclic. Bounded spins.
__global__ __launch_bounds__(256, 1)
void lstm_fused(const unsigned short* __restrict__ Gcur, unsigned short* __restrict__ Gnext,
                const unsigned short* __restrict__ Xnext, const unsigned short* __restrict__ Wih,
                const unsigned short* __restrict__ Whh,
                unsigned short* __restrict__ h0, unsigned short* __restrict__ h1,
                float* __restrict__ c_state, unsigned* __restrict__ flags,
                unsigned* __restrict__ pflags, float* __restrict__ partials,
                int t0, int do_gemm,
                float* __restrict__ out_h, float* __restrict__ out_c)
{
    __shared__ __align__(16) char smem[2 * 128 * 72 * 2];   // 36 KB (gemm As/Bs; recurrence red 16 KB)

    const int tid = threadIdx.x;

    if (blockIdx.x >= 128) {
        // ---- GEMM half: 8 tiles of G2(next chunk); no sync participation ----
        if (!do_gemm) return;
        unsigned short (*As)[72] = reinterpret_cast<unsigned short(*)[72]>(smem);
        unsigned short (*Bs)[72] = reinterpret_cast<unsigned short(*)[72]>(smem + 128 * 72 * 2);
        const int base = (blockIdx.x - 128) * 8;
        for (int tt = 0; tt < 8; ++tt) {
            const int tile = base + tt;
            gemm_tile(Xnext, Wih, Gnext, tile & 31, tile >> 5, As, Bs, tid);
        }
        return;
    }

    // ---- recurrence half ----
    typedef float RedT[2][4][64][4];                 // per rh: [rt][ct][lane][r], 8 KB
    RedT* red = reinterpret_cast<RedT*>(smem);       // red[rh], 16 KB total

    const int b = blockIdx.x;
    const int front = (b < 64) ? 1 : 0;
    const int pb = front ? b : (b - 64);
    const int w = tid >> 6, l = tid & 63;
    const int kh2 = w & 1, rh = w >> 1;
    const int lc = l & 15;
    const int koff = (l >> 4) * 8;
    const int kbase = (front ? 0 : 512) + kh2 * 256;

    // W_hh fragments -> 128 VGPRs (once per launch): 4 col-tiles x K-quarter
    short8 breg[4][8];
#pragma unroll
    for (int ct = 0; ct < 4; ++ct) {
        const unsigned short* wrow =
            Whh + (size_t)(ct * Hn + pb * 16 + lc) * Hn + kbase + koff;
#pragma unroll
        for (int j = 0; j < 8; ++j)
            breg[ct][j] = *reinterpret_cast<const short8*>(wrow + j * 32);
    }

    // c-state in registers (front kh2==0 waves own the cell)
    float c_reg[2][4];
    if (front && kh2 == 0) {
#pragma unroll
        for (int rt = 0; rt < 2; ++rt)
#pragma unroll
            for (int r = 0; r < 4; ++r)
                c_reg[rt][r] = c_state[(rh * 32 + rt * 16 + (l >> 4) * 4 + r) * Hn + pb * 16 + lc];
    }

    // G2 prefetch s=0 (front kh2==0): ushort4 = 4 rows of one gate-col
    ushort4 gp[2][4];
    if (front && kh2 == 0) {
#pragma unroll
        for (int rt = 0; rt < 2; ++rt)
#pragma unroll
            for (int ct = 0; ct < 4; ++ct)
                gp[rt][ct] = *reinterpret_cast<const ushort4*>(
                    Gcur + (size_t)(ct * 1024 + pb * 16 + lc) * 64 + rh * 32 + rt * 16 + (l >> 4) * 4);
    }

    for (int s = 0; s < CHUNK; ++s) {
        const int t = t0 + s;
        const unsigned short* hin = (t & 1) ? h1 : h0;
        unsigned short* hout = (t & 1) ? h0 : h1;

        // ---- rigid barrier on the 64 FRONT flags (h(t) ready + reuse guard) ----
        {
            unsigned fv = __hip_atomic_load(&flags[l * 32], __ATOMIC_RELAXED, AGENT);
            int g = 0;
            while (__any(fv < (unsigned)t) && g < (1 << 16)) {
                __builtin_amdgcn_s_sleep(1);
                fv = __hip_atomic_load(&flags[l * 32], __ATOMIC_RELAXED, AGENT);
                ++g;
            }
        }
        __builtin_amdgcn_sched_barrier(0);

        const unsigned short* ap0 = hin + (size_t)(rh * 32 + lc) * Hn + kbase + koff;
        const unsigned short* ap1 = hin + (size_t)(rh * 32 + 16 + lc) * Hn + kbase + koff;

        f32x4 acc[2][4];
#pragma unroll
        for (int rt = 0; rt < 2; ++rt)
#pragma unroll
            for (int ct = 0; ct < 4; ++ct) acc[rt][ct] = (f32x4){0.f, 0.f, 0.f, 0.f};

        u32x4 bufA[8], bufB[8];
        ISSUE_GRP(bufA, 0,   64,  128, 192);   // j = 0..3 of this K-quarter
        ISSUE_GRP(bufB, 256, 320, 384, 448);   // j = 4..7

        VMW(8); MFMA_G4(bufA, 0);
        VMW(0); MFMA_G4(bufB, 4);

        // intra-block K-quarter reduction via LDS
        if (kh2 == 1) {
#pragma unroll
            for (int rt = 0; rt < 2; ++rt)
#pragma unroll
                for (int ct = 0; ct < 4; ++ct)
                    *reinterpret_cast<f32x4*>(&red[rh][rt][ct][l][0]) = acc[rt][ct];
        }
        __syncthreads();

        if (kh2 == 0) {
#pragma unroll
            for (int rt = 0; rt < 2; ++rt)
#pragma unroll
                for (int ct = 0; ct < 4; ++ct)
                    acc[rt][ct] = acc[rt][ct] + *reinterpret_cast<f32x4*>(&red[rh][rt][ct][l][0]);

            float* Pp = partials + (size_t)(pb * 2 + (t & 1)) * 4096 + (rh * 64 + l) * 32;

            if (front) {
                // wait for partner's K-half partial
                {
                    unsigned pv = __hip_atomic_load(&pflags[pb * 32], __ATOMIC_RELAXED, AGENT);
                    int g = 0;
                    while (__any(pv < (unsigned)(t + 1)) && g < (1 << 16)) {
                        __builtin_amdgcn_s_sleep(1);
                        pv = __hip_atomic_load(&pflags[pb * 32], __ATOMIC_RELAXED, AGENT);
                        ++g;
                    }
                }
                __builtin_amdgcn_sched_barrier(0);
                u32x4 pp[8];
                LDH(pp[0], Pp, 0);  LDH(pp[1], Pp, 16); LDH(pp[2], Pp, 32);  LDH(pp[3], Pp, 48);
                LDH(pp[4], Pp, 64); LDH(pp[5], Pp, 80); LDH(pp[6], Pp, 96);  LDH(pp[7], Pp, 112);
                VMW(0);
#pragma unroll
                for (int rt = 0; rt < 2; ++rt)
#pragma unroll
                    for (int ct = 0; ct < 4; ++ct) {
                        union { u32x4 u; f32x4 f; } cv; cv.u = pp[rt * 4 + ct];
                        acc[rt][ct] = acc[rt][ct] + cv.f;
                    }

                // ---- cell: all 4 gates lane-local ----
#pragma unroll
                for (int rt = 0; rt < 2; ++rt) {
                    const unsigned short* gi = reinterpret_cast<const unsigned short*>(&gp[rt][0]);
                    const unsigned short* gf = reinterpret_cast<const unsigned short*>(&gp[rt][1]);
                    const unsigned short* gg = reinterpret_cast<const unsigned short*>(&gp[rt][2]);
                    const unsigned short* go = reinterpret_cast<const unsigned short*>(&gp[rt][3]);
#pragma unroll
                    for (int r = 0; r < 4; ++r) {
                        float iv = acc[rt][0][r] + bf2f(gi[r]);
                        float fv = acc[rt][1][r] + bf2f(gf[r]);
                        float gv = acc[rt][2][r] + bf2f(gg[r]);
                        float ov = acc[rt][3][r] + bf2f(go[r]);
                        float cn = sigm(fv) * c_reg[rt][r] + sigm(iv) * tanh_fast(gv);
                        float hn = sigm(ov) * tanh_fast(cn);
                        c_reg[rt][r] = cn;
                        const int row = rh * 32 + rt * 16 + (l >> 4) * 4 + r;
                        unsigned hb = f2bf(hn);
                        unsigned partner = (unsigned)__shfl_xor((int)hb, 1);
                        if (!(l & 1)) {
                            unsigned val = (hb & 0xFFFFu) | (partner << 16);
                            __hip_atomic_store(
                                (unsigned*)(hout + (size_t)row * Hn + pb * 16 + lc),
                                val, __ATOMIC_RELAXED, AGENT);
                        }
                        if (t == Tn - 1) {
                            out_h[row * Hn + pb * 16 + lc] = hn;
                            out_c[row * Hn + pb * 16 + lc] = cn;
                        }
                    }
                }
                asm volatile("s_waitcnt vmcnt(0)" ::: "memory");   // drain h stores
            } else {
                // back: publish partial in front's acc layout (8 x 16B)
                union { f32x4 f; u32x4 u; } d;
                d.f = acc[0][0]; STHI(Pp, d.u, 0);
                d.f = acc[0][1]; STHI(Pp, d.u, 16);
                d.f = acc[0][2]; STHI(Pp, d.u, 32);
                d.f = acc[0][3]; STHI(Pp, d.u, 48);
                d.f = acc[1][0]; STHI(Pp, d.u, 64);
                d.f = acc[1][1]; STHI(Pp, d.u, 80);
                d.f = acc[1][2]; STHI(Pp, d.u, 96);
                d.f = acc[1][3]; STHI(Pp, d.u, 112);
                asm volatile("s_waitcnt vmcnt(0)" ::: "memory");   // drain partial
            }
        }
        __syncthreads();

        if (tid == 0) {
            if (front)
                __hip_atomic_store(&flags[b * 32], (unsigned)(t + 1), __ATOMIC_RELAXED, AGENT);
            else
                __hip_atomic_store(&pflags[pb * 32], (unsigned)(t + 1), __ATOMIC_RELAXED, AGENT);
        }

        // G2 prefetch s+1 (front): sits in queue, drained by next step's poll
        if (front && kh2 == 0 && s + 1 < CHUNK) {
            const unsigned short* Gt = Gcur + (size_t)(s + 1) * 262144;
#pragma unroll
            for (int rt = 0; rt < 2; ++rt)
#pragma unroll
                for (int ct = 0; ct < 4; ++ct)
                    gp[rt][ct] = *reinterpret_cast<const ushort4*>(
                        Gt + (size_t)(ct * 1024 + pb * 16 + lc) * 64 + rh * 32 + rt * 16 + (l >> 4) * 4);
        }
    }

    if (front && kh2 == 0) {
#pragma unroll
        for (int rt = 0; rt < 2; ++rt)
#pragma unroll
            for (int r = 0; r < 4; ++r)
                c_state[(rh * 32 + rt * 16 + (l >> 4) * 4 + r) * Hn + pb * 16 + lc] = c_reg[rt][r];
    }
}

// ---------------- classifier: logits[64,V] = h @ W_cls^T + b ----------------
__global__ __launch_bounds__(256)
void classifier(const unsigned short* __restrict__ h,
                const float* __restrict__ Wcls, const float* __restrict__ bcls,
                float* __restrict__ logits)
{
    __shared__ __align__(16) unsigned short Al[64][72];
    __shared__ __align__(16) unsigned short Bl[64][72];

    const int tid = threadIdx.x;
    const int v0 = blockIdx.x * 64;
    const int w = tid >> 6, l = tid & 63;
    const int lrow = tid >> 2, q = tid & 3;
    const int v = v0 + lrow;

    const unsigned short* hrow = h + lrow * Hn;
    const float* wrow = Wcls + (size_t)v * Hn;

    f32x4 acc[4];
#pragma unroll
    for (int ct = 0; ct < 4; ++ct) acc[ct] = (f32x4){0.f, 0.f, 0.f, 0.f};

    const int arow = w * 16 + (l & 15);
    const int koff = (l >> 4) * 8;

    for (int ch = 0; ch < 16; ++ch) {
        const int k0 = ch * 64;
        __syncthreads();
#pragma unroll
        for (int i2 = 0; i2 < 4; ++i2) {
            const int k = q * 4 + i2 * 16;
            *reinterpret_cast<ushort4*>(&Al[lrow][k]) =
                *reinterpret_cast<const ushort4*>(hrow + k0 + k);
            if (v < Vn) {
                float4 x = *reinterpret_cast<const float4*>(wrow + k0 + k);
                Bl[lrow][k + 0] = f2bf(x.x); Bl[lrow][k + 1] = f2bf(x.y);
                Bl[lrow][k + 2] = f2bf(x.z); Bl[lrow][k + 3] = f2bf(x.w);
            } else {
                ushort4 z; z.x = z.y = z.z = z.w = 0;
                *reinterpret_cast<ushort4*>(&Bl[lrow][k]) = z;
            }
        }
        __syncthreads();

        short8 a0 = *reinterpret_cast<const short8*>(&Al[arow][koff]);
        short8 a1 = *reinterpret_cast<const short8*>(&Al[arow][32 + koff]);
#pragma unroll
        for (int ct = 0; ct < 4; ++ct) {
            const int bcol = ct * 16 + (l & 15);
            short8 b0 = *reinterpret_cast<const short8*>(&Bl[bcol][koff]);
            short8 b1 = *reinterpret_cast<const short8*>(&Bl[bcol][32 + koff]);
            acc[ct] = __builtin_amdgcn_mfma_f32_16x16x32_bf16(a0, b0, acc[ct], 0, 0, 0);
            acc[ct] = __builtin_amdgcn_mfma_f32_16x16x32_bf16(a1, b1, acc[ct], 0, 0, 0);
        }
    }

    const int rr0 = w * 16 + (l >> 4) * 4;
#pragma unroll
    for (int ct = 0; ct < 4; ++ct) {
        const int vv = v0 + ct * 16 + (l & 15);
        if (vv < Vn) {
            float bb = bcls[vv];
#pragma unroll
            for (int r = 0; r < 4; ++r)
                logits[(size_t)(rr0 + r) * Vn + vv] = acc[ct][r] + bb;
        }
    }
}

extern "C" void kernel_launch(void* const* d_in, const int* in_sizes, int n_in,
                              void* d_out, int out_size, void* d_ws, size_t ws_size,
                              hipStream_t stream)
{
    const int*   tokens = (const int*)d_in[0];
    const float* emb    = (const float*)d_in[1];
    const float* W_ih   = (const float*)d_in[2];
    const float* W_hh   = (const float*)d_in[3];
    const float* W_cls  = (const float*)d_in[4];
    const float* b_cls  = (const float*)d_in[5];
    float* out = (float*)d_out;

    // ws layout (~90.5 MB):
    // [h0 128K][h1 128K][c 256K][flags 16K][pflags 16K][partials 2M]
    // [Wih 8M][Whh 8M][X 8M][G2_0 32M][G2_1 32M]
    char* ws = (char*)d_ws;
    unsigned short* hbuf0  = (unsigned short*)ws;
    unsigned short* hbuf1  = (unsigned short*)(ws + 131072);
    float*          cst    = (float*)(ws + 262144);
    unsigned*       flags  = (unsigned*)(ws + 524288);
    unsigned*       pflags = (unsigned*)(ws + 540672);
    float*          parts  = (float*)(ws + 557056);
    unsigned short* Wih_b  = (unsigned short*)(ws + 2654208);
    unsigned short* Whh_b  = (unsigned short*)(ws + 2654208 + 8388608);
    unsigned short* Xb     = (unsigned short*)(ws + 2654208 + 2 * 8388608);
    unsigned short* Gb0    = (unsigned short*)(ws + 2654208 + 3 * 8388608);
    unsigned short* Gb1    = (unsigned short*)(ws + 2654208 + 3 * 8388608 + 33554432);

    // zero h(0), c(0), flags, pflags each call (partials always written before read)
    hipMemsetAsync(ws, 0, 557056, stream);

    const int n4 = (4 * Hn * En) / 4;
    cvt_f32_bf16<<<n4 / 256, 256, 0, stream>>>(W_ih, Wih_b, n4);
    cvt_f32_bf16<<<n4 / 256, 256, 0, stream>>>(W_hh, Whh_b, n4);

    float* out_h = out + (size_t)Bn * Vn;
    float* out_c = out_h + Bn * Hn;

    // chunk 0: gather + standalone gemm (transposed G2)
    gather_x<<<CHUNK * Bn, 256, 0, stream>>>(tokens, emb, Xb, 0);
    gemm_gin<<<32 * 32, 256, 0, stream>>>(Xb, Wih_b, Gb0);

    unsigned short* Gbuf[2] = {Gb0, Gb1};
    for (int c = 0; c < NCHUNK; ++c) {
        const int do_gemm = (c + 1 < NCHUNK) ? 1 : 0;
        if (do_gemm)
            gather_x<<<CHUNK * Bn, 256, 0, stream>>>(tokens, emb, Xb, (c + 1) * CHUNK);
        lstm_fused<<<256, 256, 0, stream>>>(Gbuf[c & 1], Gbuf[(c + 1) & 1], Xb,
                                            Wih_b, Whh_b, hbuf0, hbuf1,
                                            cst, flags, pflags, parts,
                                            c * CHUNK, do_gemm, out_h, out_c);
    }

    // h(512): step 511 wrote slot (511+1)&1 = 0 -> hbuf0
    classifier<<<(Vn + 63) / 64, 256, 0, stream>>>(hbuf0, W_cls, b_cls, out);
}

// Round 16
// 4115.898 us; speedup vs baseline: 1.6084x; 1.2230x over previous
//
#include <hip/hip_runtime.h>

// Problem dims (fixed)
#define Bn 64
#define Tn 512
#define En 1024
#define Hn 1024
#define Vn 50257
#define CHUNK 64
#define NCHUNK (Tn / CHUNK)
#define AGENT __HIP_MEMORY_SCOPE_AGENT

typedef __attribute__((ext_vector_type(8))) short short8;
typedef __attribute__((ext_vector_type(4))) float f32x4;
typedef __attribute__((ext_vector_type(4))) unsigned int u32x4;

__device__ __forceinline__ unsigned short f2bf(float f) {
    union { float f; unsigned u; } x; x.f = f;
    unsigned r = x.u + 0x7FFFu + ((x.u >> 16) & 1u);   // RNE; values are tame
    return (unsigned short)(r >> 16);
}
__device__ __forceinline__ float bf2f(unsigned short u) {
    union { unsigned u; float f; } x; x.u = ((unsigned)u) << 16; return x.f;
}
__device__ __forceinline__ float sigm(float x) { return 1.0f / (1.0f + __expf(-x)); }
__device__ __forceinline__ float tanh_fast(float x) {
    float e = __expf(2.0f * x);
    return (e - 1.0f) / (e + 1.0f);
}

// 16B IC-coherent load (bypasses L1/L2 -> coherent at Infinity Cache)
#define LDH(dst, base, IMM)                                                  \
    asm volatile("global_load_dwordx4 %0, %1, off offset:" #IMM " sc0 sc1"   \
                 : "=v"(dst) : "v"(base) : "memory")
// counted wait + scheduler fence (rule #18)
#define VMW(N) do { asm volatile("s_waitcnt vmcnt(" #N ")" ::: "memory");    \
                    __builtin_amdgcn_sched_barrier(0); } while (0)
// issue 16 16B h-loads for one stream (16 rows x K-half; 1 row-tile)
#define ISSUE16(buf, ap)                                                     \
    do {                                                                     \
        LDH((buf)[0],  ap, 0);   LDH((buf)[1],  ap, 64);                     \
        LDH((buf)[2],  ap, 128); LDH((buf)[3],  ap, 192);                    \
        LDH((buf)[4],  ap, 256); LDH((buf)[5],  ap, 320);                    \
        LDH((buf)[6],  ap, 384); LDH((buf)[7],  ap, 448);                    \
        LDH((buf)[8],  ap, 512); LDH((buf)[9],  ap, 576);                    \
        LDH((buf)[10], ap, 640); LDH((buf)[11], ap, 704);                    \
        LDH((buf)[12], ap, 768); LDH((buf)[13], ap, 832);                    \
        LDH((buf)[14], ap, 896); LDH((buf)[15], ap, 960);                    \
    } while (0)
// consume a stream's 16 fragments against breg[ct][0..15]
#define MFMA16(buf, a0, a1)                                                  \
    do {                                                                     \
        _Pragma("unroll")                                                    \
        for (int jj = 0; jj < 16; ++jj) {                                    \
            union { u32x4 u; short8 s; } fz; fz.u = (buf)[jj];               \
            a0 = __builtin_amdgcn_mfma_f32_16x16x32_bf16(fz.s, breg[0][jj], a0, 0, 0, 0); \
            a1 = __builtin_amdgcn_mfma_f32_16x16x32_bf16(fz.s, breg[1][jj], a1, 0, 0, 0); \
        }                                                                    \
    } while (0)
// all-128 poll on flag array F (targets tgt); lanes cover 2 flags each
#define POLL128(F, tgt)                                                      \
    do {                                                                     \
        unsigned fa_ = __hip_atomic_load(&(F)[l * 32], __ATOMIC_RELAXED, AGENT);       \
        unsigned fb_ = __hip_atomic_load(&(F)[(64 + l) * 32], __ATOMIC_RELAXED, AGENT);\
        int g_ = 0;                                                          \
        while (__any((fa_ < (unsigned)(tgt)) || (fb_ < (unsigned)(tgt))) && g_ < (1 << 16)) { \
            __builtin_amdgcn_s_sleep(1);                                     \
            fa_ = __hip_atomic_load(&(F)[l * 32], __ATOMIC_RELAXED, AGENT);            \
            fb_ = __hip_atomic_load(&(F)[(64 + l) * 32], __ATOMIC_RELAXED, AGENT);     \
            ++g_;                                                            \
        }                                                                    \
        __builtin_amdgcn_sched_barrier(0);                                   \
    } while (0)

// ---------------- fp32 -> bf16 weight convert ----------------
__global__ __launch_bounds__(256)
void cvt_f32_bf16(const float* __restrict__ src, unsigned short* __restrict__ dst, int n4) {
    int i = blockIdx.x * 256 + threadIdx.x;
    if (i < n4) {
        float4 v = reinterpret_cast<const float4*>(src)[i];
        ushort4 o;
        o.x = f2bf(v.x); o.y = f2bf(v.y); o.z = f2bf(v.z); o.w = f2bf(v.w);
        reinterpret_cast<ushort4*>(dst)[i] = o;
    }
}

// ---------------- embedding gather for one 64-step chunk ----------------
__global__ __launch_bounds__(256)
void gather_x(const int* __restrict__ tokens, const float* __restrict__ emb,
              unsigned short* __restrict__ X, int t0) {
    const int r = blockIdx.x;
    const int trel = r >> 6, b = r & 63;
    const int tok = tokens[b * Tn + t0 + trel];
    const float* src = emb + (size_t)tok * En;
    const int k = threadIdx.x * 4;
    float4 v = *reinterpret_cast<const float4*>(src + k);
    ushort4 o;
    o.x = f2bf(v.x); o.y = f2bf(v.y); o.z = f2bf(v.z); o.w = f2bf(v.w);
    *reinterpret_cast<ushort4*>(X + (size_t)r * En + k) = o;
}

// ---- shared gemm tile body: one 128x128 tile of X @ Wih^T (bf16 out) ----
__device__ __forceinline__ void gemm_tile(
    const unsigned short* __restrict__ X, const unsigned short* __restrict__ Wih,
    unsigned short* __restrict__ G, int bx, int by,
    unsigned short (*As)[72], unsigned short (*Bs)[72], int tid)
{
    const int w = tid >> 6, l = tid & 63;
    const int wr = w >> 1, wc = w & 1;
    const int koff = (l >> 4) * 8;

    f32x4 acc[4][4];
#pragma unroll
    for (int i = 0; i < 4; ++i)
#pragma unroll
        for (int j = 0; j < 4; ++j) acc[i][j] = (f32x4){0.f, 0.f, 0.f, 0.f};

    for (int kk = 0; kk < En / 64; ++kk) {
        __syncthreads();
#pragma unroll
        for (int j = 0; j < 4; ++j) {
            const int u = tid * 4 + j;
            const int row = u >> 3, ku = (u & 7) * 8;
            *reinterpret_cast<short8*>(&As[row][ku]) =
                *reinterpret_cast<const short8*>(X + (size_t)(by * 128 + row) * En + kk * 64 + ku);
            *reinterpret_cast<short8*>(&Bs[row][ku]) =
                *reinterpret_cast<const short8*>(Wih + (size_t)(bx * 128 + row) * En + kk * 64 + ku);
        }
        __syncthreads();

#pragma unroll
        for (int kc = 0; kc < 2; ++kc) {
            const int k0 = kc * 32 + koff;
            short8 af[4], bf[4];
#pragma unroll
            for (int i = 0; i < 4; ++i)
                af[i] = *reinterpret_cast<const short8*>(&As[wr * 64 + i * 16 + (l & 15)][k0]);
#pragma unroll
            for (int j = 0; j < 4; ++j)
                bf[j] = *reinterpret_cast<const short8*>(&Bs[wc * 64 + j * 16 + (l & 15)][k0]);
#pragma unroll
            for (int i = 0; i < 4; ++i)
#pragma unroll
                for (int j = 0; j < 4; ++j)
                    acc[i][j] = __builtin_amdgcn_mfma_f32_16x16x32_bf16(af[i], bf[j], acc[i][j], 0, 0, 0);
        }
    }

    const int rr = 4 * (l >> 4);
#pragma unroll
    for (int i = 0; i < 4; ++i) {
        const int row = by * 128 + wr * 64 + i * 16 + rr;
#pragma unroll
        for (int j = 0; j < 4; ++j) {
            const int col = bx * 128 + wc * 64 + j * 16 + (l & 15);
#pragma unroll
            for (int r = 0; r < 4; ++r)
                G[(size_t)(row + r) * 4096 + col] = f2bf(acc[i][j][r]);
        }
    }
}

// ---------------- standalone G = X @ W_ih^T (chunk 0 only), bf16 out ----------------
__global__ __launch_bounds__(256)
void gemm_gin(const unsigned short* __restrict__ X, const unsigned short* __restrict__ Wih,
              unsigned short* __restrict__ G) {
    __shared__ __align__(16) unsigned short As[128][72];
    __shared__ __align__(16) unsigned short Bs[128][72];
    gemm_tile(X, Wih, G, blockIdx.x & 31, blockIdx.x >> 5, As, Bs, threadIdx.x);
}

// ---------------- fused: 2-stream recurrence (0-127) + next-chunk GEMM (128-255) ----
// TWO BATCH STREAMS time-multiplexed per block: A = rows 0-31, B = rows 32-63
// (independent recurrences). Round = one step of each; each stream's poll /
// load-flight hides under the other's phases. Per wave per stream: 16 rows x
// K-half = 16x16B loads + 32 MFMA (breg shared between streams). Sound
// double-buffer invariant per stream (all-128 poll precedes same-round write).
__global__ __launch_bounds__(256, 1)
void lstm_fused(const unsigned short* __restrict__ Gcur, unsigned short* __restrict__ Gnext,
                const unsigned short* __restrict__ Xnext, const unsigned short* __restrict__ Wih,
                const unsigned short* __restrict__ Whh,
                unsigned short* __restrict__ h0, unsigned short* __restrict__ h1,
                float* __restrict__ c_state, unsigned* __restrict__ flagsA,
                unsigned* __restrict__ flagsB, int t0, int do_gemm,
                float* __restrict__ out_h, float* __restrict__ out_c)
{
    __shared__ __align__(16) char smem[2 * 128 * 72 * 2];   // 36 KB (gemm As/Bs; recurrence redA/redB 8 KB)

    const int tid = threadIdx.x;

    if (blockIdx.x >= 128) {
        // ---- GEMM half: 8 tiles of G(next chunk); no sync participation ----
        if (!do_gemm) return;
        unsigned short (*As)[72] = reinterpret_cast<unsigned short(*)[72]>(smem);
        unsigned short (*Bs)[72] = reinterpret_cast<unsigned short(*)[72]>(smem + 128 * 72 * 2);
        const int base = (blockIdx.x - 128) * 8;
        for (int tt = 0; tt < 8; ++tt) {
            const int tile = base + tt;
            gemm_tile(Xnext, Wih, Gnext, tile & 31, tile >> 5, As, Bs, tid);
        }
        return;
    }

    // ---- recurrence half ----
    typedef float RedT[2][2][64][4];                 // [rh][ct][lane][r], 4 KB
    RedT* redA = reinterpret_cast<RedT*>(smem);
    RedT* redB = reinterpret_cast<RedT*>(smem + 4096);

    const int b = blockIdx.x;
    const int w = tid >> 6, l = tid & 63;
    const int kh = w & 1, rh = w >> 1;
    const int koff = (l >> 4) * 8;
    const int lc = l & 15;
    const int hcol = b * 8 + (l & 7);

    // W_hh fragments -> registers (shared by both streams)
    short8 breg[2][16];
#pragma unroll
    for (int ct = 0; ct < 2; ++ct) {
        const int gate = ct * 2 + (lc >> 3);
        const unsigned short* wrow = Whh + ((size_t)gate * Hn + (b * 8 + (lc & 7))) * Hn;
#pragma unroll
        for (int j = 0; j < 16; ++j)
            breg[ct][j] = *reinterpret_cast<const short8*>(wrow + (kh * 16 + j) * 32 + koff);
    }

    const int rowbase = rh * 16 + ((l >> 4) << 2);   // stream-local cell rows

    // c-state (kh==0 waves own cells), per stream
    float cA[4], cB[4];
    if (kh == 0) {
#pragma unroll
        for (int r = 0; r < 4; ++r) {
            cA[r] = c_state[(rowbase + r) * Hn + hcol];
            cB[r] = c_state[(32 + rowbase + r) * Hn + hcol];
        }
    }

    const int sg = lc >> 3;
    const int gc0 = sg * Hn + hcol;          // i (sg=0) / f (sg=1)
    const int gc1 = (2 + sg) * Hn + hcol;    // g / o

    // G prefetch s=0, both streams (kh0)
    unsigned short gA0[4], gA1[4], gB0[4], gB1[4];
    if (kh == 0) {
#pragma unroll
        for (int r = 0; r < 4; ++r) {
            gA0[r] = Gcur[(size_t)(rowbase + r) * 4096 + gc0];
            gA1[r] = Gcur[(size_t)(rowbase + r) * 4096 + gc1];
            gB0[r] = Gcur[(size_t)(32 + rowbase + r) * 4096 + gc0];
            gB1[r] = Gcur[(size_t)(32 + rowbase + r) * 4096 + gc1];
        }
    }

    const int arow = rh * 16 + (l & 15);     // stream-local A-fragment row

    for (int s = 0; s < CHUNK; ++s) {
        const int t = t0 + s;
        const unsigned short* hin = (t & 1) ? h1 : h0;
        unsigned short* hout = (t & 1) ? h0 : h1;

        // ---- poll A, issue A ----
        POLL128(flagsA, t);
        const unsigned short* apA = hin + (size_t)arow * Hn + kh * 512 + koff;
        u32x4 bufA[16];
        ISSUE16(bufA, apA);

        // ---- poll B (first flag use drains A's flight), issue B ----
        POLL128(flagsB, t);
        const unsigned short* apB = hin + (size_t)(32 + arow) * Hn + kh * 512 + koff;
        u32x4 bufB[16];
        ISSUE16(bufB, apB);

        // ---- stream A compute (data resident after pollB's drain) ----
        f32x4 aA0 = (f32x4){0.f, 0.f, 0.f, 0.f};
        f32x4 aA1 = (f32x4){0.f, 0.f, 0.f, 0.f};
        MFMA16(bufA, aA0, aA1);
        if (kh == 1) {
            *reinterpret_cast<f32x4*>(&(*redA)[rh][0][l][0]) = aA0;
            *reinterpret_cast<f32x4*>(&(*redA)[rh][1][l][0]) = aA1;
        }
        __syncthreads();
        if (kh == 0) {
            f32x4 a0 = aA0 + *reinterpret_cast<f32x4*>(&(*redA)[rh][0][l][0]);
            f32x4 a1 = aA1 + *reinterpret_cast<f32x4*>(&(*redA)[rh][1][l][0]);
#pragma unroll
            for (int r = 0; r < 4; ++r) {
                float v0 = a0[r] + bf2f(gA0[r]);
                float v1 = a1[r] + bf2f(gA1[r]);
                float p0 = __shfl_xor(v0, 8);
                float p1 = __shfl_xor(v1, 8);
                float iv = (l & 8) ? p0 : v0;
                float fv = (l & 8) ? v0 : p0;
                float gv = (l & 8) ? p1 : v1;
                float ov = (l & 8) ? v1 : p1;
                float cn = sigm(fv) * cA[r] + sigm(iv) * tanh_fast(gv);
                float hn = sigm(ov) * tanh_fast(cn);
                cA[r] = cn;
                unsigned hb = f2bf(hn);
                unsigned partner = (unsigned)__shfl_xor((int)hb, 1);
                if (!(l & 8) && !(l & 1)) {
                    unsigned val = (hb & 0xFFFFu) | (partner << 16);
                    __hip_atomic_store((unsigned*)(hout + (size_t)(rowbase + r) * Hn + hcol),
                                       val, __ATOMIC_RELAXED, AGENT);
                }
                if (t == Tn - 1 && !(l & 8)) {
                    out_h[(rowbase + r) * Hn + hcol] = hn;
                    out_c[(rowbase + r) * Hn + hcol] = cn;
                }
            }
        }
        asm volatile("s_waitcnt vmcnt(0)" ::: "memory");   // drain hA stores (and B loads)
        __syncthreads();
        if (tid == 0)
            __hip_atomic_store(&flagsA[b * 32], (unsigned)(t + 1), __ATOMIC_RELAXED, AGENT);

        // ---- stream B compute (data resident) ----
        f32x4 aB0 = (f32x4){0.f, 0.f, 0.f, 0.f};
        f32x4 aB1 = (f32x4){0.f, 0.f, 0.f, 0.f};
        MFMA16(bufB, aB0, aB1);
        if (kh == 1) {
            *reinterpret_cast<f32x4*>(&(*redB)[rh][0][l][0]) = aB0;
            *reinterpret_cast<f32x4*>(&(*redB)[rh][1][l][0]) = aB1;
        }
        __syncthreads();
        if (kh == 0) {
            f32x4 a0 = aB0 + *reinterpret_cast<f32x4*>(&(*redB)[rh][0][l][0]);
            f32x4 a1 = aB1 + *reinterpret_cast<f32x4*>(&(*redB)[rh][1][l][0]);
#pragma unroll
            for (int r = 0; r < 4; ++r) {
                float v0 = a0[r] + bf2f(gB0[r]);
                float v1 = a1[r] + bf2f(gB1[r]);
                float p0 = __shfl_xor(v0, 8);
                float p1 = __shfl_xor(v1, 8);
                float iv = (l & 8) ? p0 : v0;
                float fv = (l & 8) ? v0 : p0;
                float gv = (l & 8) ? p1 : v1;
                float ov = (l & 8) ? v1 : p1;
                float cn = sigm(fv) * cB[r] + sigm(iv) * tanh_fast(gv);
                float hn = sigm(ov) * tanh_fast(cn);
                cB[r] = cn;
                unsigned hb = f2bf(hn);
                unsigned partner = (unsigned)__shfl_xor((int)hb, 1);
                if (!(l & 8) && !(l & 1)) {
                    unsigned val = (hb & 0xFFFFu) | (partner << 16);
                    __hip_atomic_store((unsigned*)(hout + (size_t)(32 + rowbase + r) * Hn + hcol),
                                       val, __ATOMIC_RELAXED, AGENT);
                }
                if (t == Tn - 1 && !(l & 8)) {
                    out_h[(32 + rowbase + r) * Hn + hcol] = hn;
                    out_c[(32 + rowbase + r) * Hn + hcol] = cn;
                }
            }
        }
        asm volatile("s_waitcnt vmcnt(0)" ::: "memory");   // drain hB stores
        __syncthreads();
        if (tid == 0)
            __hip_atomic_store(&flagsB[b * 32], (unsigned)(t + 1), __ATOMIC_RELAXED, AGENT);

        // ---- G prefetch (t+1), both streams; retired by next round's pollA ----
        if (kh == 0 && s + 1 < CHUNK) {
            const unsigned short* Gt = Gcur + (size_t)(s + 1) * Bn * 4096;
#pragma unroll
            for (int r = 0; r < 4; ++r) {
                gA0[r] = Gt[(size_t)(rowbase + r) * 4096 + gc0];
                gA1[r] = Gt[(size_t)(rowbase + r) * 4096 + gc1];
                gB0[r] = Gt[(size_t)(32 + rowbase + r) * 4096 + gc0];
                gB1[r] = Gt[(size_t)(32 + rowbase + r) * 4096 + gc1];
            }
        }
    }

    if (kh == 0 && !(l & 8)) {
#pragma unroll
        for (int r = 0; r < 4; ++r) {
            c_state[(rowbase + r) * Hn + hcol] = cA[r];
            c_state[(32 + rowbase + r) * Hn + hcol] = cB[r];
        }
    }
}

// ---------------- classifier: logits[64,V] = h @ W_cls^T + b ----------------
__global__ __launch_bounds__(256)
void classifier(const unsigned short* __restrict__ h,
                const float* __restrict__ Wcls, const float* __restrict__ bcls,
                float* __restrict__ logits)
{
    __shared__ __align__(16) unsigned short Al[64][72];
    __shared__ __align__(16) unsigned short Bl[64][72];

    const int tid = threadIdx.x;
    const int v0 = blockIdx.x * 64;
    const int w = tid >> 6, l = tid & 63;
    const int lrow = tid >> 2, q = tid & 3;
    const int v = v0 + lrow;

    const unsigned short* hrow = h + lrow * Hn;
    const float* wrow = Wcls + (size_t)v * Hn;

    f32x4 acc[4];
#pragma unroll
    for (int ct = 0; ct < 4; ++ct) acc[ct] = (f32x4){0.f, 0.f, 0.f, 0.f};

    const int arow = w * 16 + (l & 15);
    const int koff = (l >> 4) * 8;

    for (int ch = 0; ch < 16; ++ch) {
        const int k0 = ch * 64;
        __syncthreads();
#pragma unroll
        for (int i2 = 0; i2 < 4; ++i2) {
            const int k = q * 4 + i2 * 16;
            *reinterpret_cast<ushort4*>(&Al[lrow][k]) =
                *reinterpret_cast<const ushort4*>(hrow + k0 + k);
            if (v < Vn) {
                float4 x = *reinterpret_cast<const float4*>(wrow + k0 + k);
                Bl[lrow][k + 0] = f2bf(x.x); Bl[lrow][k + 1] = f2bf(x.y);
                Bl[lrow][k + 2] = f2bf(x.z); Bl[lrow][k + 3] = f2bf(x.w);
            } else {
                ushort4 z; z.x = z.y = z.z = z.w = 0;
                *reinterpret_cast<ushort4*>(&Bl[lrow][k]) = z;
            }
        }
        __syncthreads();

        short8 a0 = *reinterpret_cast<const short8*>(&Al[arow][koff]);
        short8 a1 = *reinterpret_cast<const short8*>(&Al[arow][32 + koff]);
#pragma unroll
        for (int ct = 0; ct < 4; ++ct) {
            const int bcol = ct * 16 + (l & 15);
            short8 b0 = *reinterpret_cast<const short8*>(&Bl[bcol][koff]);
            short8 b1 = *reinterpret_cast<const short8*>(&Bl[bcol][32 + koff]);
            acc[ct] = __builtin_amdgcn_mfma_f32_16x16x32_bf16(a0, b0, acc[ct], 0, 0, 0);
            acc[ct] = __builtin_amdgcn_mfma_f32_16x16x32_bf16(a1, b1, acc[ct], 0, 0, 0);
        }
    }

    const int rr0 = w * 16 + (l >> 4) * 4;
#pragma unroll
    for (int ct = 0; ct < 4; ++ct) {
        const int vv = v0 + ct * 16 + (l & 15);
        if (vv < Vn) {
            float bb = bcls[vv];
#pragma unroll
            for (int r = 0; r < 4; ++r)
                logits[(size_t)(rr0 + r) * Vn + vv] = acc[ct][r] + bb;
        }
    }
}

extern "C" void kernel_launch(void* const* d_in, const int* in_sizes, int n_in,
                              void* d_out, int out_size, void* d_ws, size_t ws_size,
                              hipStream_t stream)
{
    const int*   tokens = (const int*)d_in[0];
    const float* emb    = (const float*)d_in[1];
    const float* W_ih   = (const float*)d_in[2];
    const float* W_hh   = (const float*)d_in[3];
    const float* W_cls  = (const float*)d_in[4];
    const float* b_cls  = (const float*)d_in[5];
    float* out = (float*)d_out;

    // ws layout (~89 MB):
    // [h0 128K][h1 128K][c 256K][flagsA 16K][flagsB 16K][Wih 8M][Whh 8M][X 8M][G0 32M][G1 32M]
    char* ws = (char*)d_ws;
    unsigned short* hbuf0  = (unsigned short*)ws;
    unsigned short* hbuf1  = (unsigned short*)(ws + 131072);
    float*          cst    = (float*)(ws + 262144);
    unsigned*       flagsA = (unsigned*)(ws + 524288);
    unsigned*       flagsB = (unsigned*)(ws + 540672);
    unsigned short* Wih_b  = (unsigned short*)(ws + 557056);
    unsigned short* Whh_b  = (unsigned short*)(ws + 557056 + 8388608);
    unsigned short* Xb     = (unsigned short*)(ws + 557056 + 2 * 8388608);
    unsigned short* Gb0    = (unsigned short*)(ws + 557056 + 3 * 8388608);
    unsigned short* Gb1    = (unsigned short*)(ws + 557056 + 3 * 8388608 + 33554432);

    // zero h(0), c(0), flagsA/B each call
    hipMemsetAsync(ws, 0, 557056, stream);

    const int n4 = (4 * Hn * En) / 4;
    cvt_f32_bf16<<<n4 / 256, 256, 0, stream>>>(W_ih, Wih_b, n4);
    cvt_f32_bf16<<<n4 / 256, 256, 0, stream>>>(W_hh, Whh_b, n4);

    float* out_h = out + (size_t)Bn * Vn;
    float* out_c = out_h + Bn * Hn;

    // chunk 0: gather + standalone gemm
    gather_x<<<CHUNK * Bn, 256, 0, stream>>>(tokens, emb, Xb, 0);
    gemm_gin<<<32 * 32, 256, 0, stream>>>(Xb, Wih_b, Gb0);

    unsigned short* Gbuf[2] = {Gb0, Gb1};
    for (int c = 0; c < NCHUNK; ++c) {
        const int do_gemm = (c + 1 < NCHUNK) ? 1 : 0;
        if (do_gemm)
            gather_x<<<CHUNK * Bn, 256, 0, stream>>>(tokens, emb, Xb, (c + 1) * CHUNK);
        lstm_fused<<<256, 256, 0, stream>>>(Gbuf[c & 1], Gbuf[(c + 1) & 1], Xb,
                                            Wih_b, Whh_b, hbuf0, hbuf1,
                                            cst, flagsA, flagsB, c * CHUNK, do_gemm,
                                            out_h, out_c);
    }

    // t=511 (odd) wrote h into hbuf0
    classifier<<<(Vn + 63) / 64, 256, 0, stream>>>(hbuf0, W_cls, b_cls, out);
}